// Round 7
// baseline (253.845 us; speedup 1.0000x reference)
//
#include <hip/hip_runtime.h>

// MultiHeadAttention: B=4, T=2048, C=1024, H=16, HS=64
// out = softmax(causal((x@Wq)(x@Wk)^T * C^-0.5)) (x@Wv)  -> concat -> @Wproj + bproj

using u16    = unsigned short;
using u32    = unsigned int;
using bf16x8 = __attribute__((ext_vector_type(8))) short;  // 8 bf16 (4 VGPRs)
using bf16x4 = __attribute__((ext_vector_type(4))) short;  // 4 bf16 (2 VGPRs)
using f32x4  = __attribute__((ext_vector_type(4))) float;  // MFMA 16x16 C/D

#define MFMA_BF16(a, b, c) __builtin_amdgcn_mfma_f32_16x16x32_bf16((a), (b), (c), 0, 0, 0)

// K=16 bf16 MFMA (v_mfma_f32_16x16x16_bf16): A/B = 4 bf16 (2 VGPRs), C/D = 4 f32
__device__ __forceinline__ f32x4 mfma16(bf16x4 a, bf16x4 b, f32x4 c) {
#if __has_builtin(__builtin_amdgcn_mfma_f32_16x16x16bf16_1k)
    return __builtin_amdgcn_mfma_f32_16x16x16bf16_1k(a, b, c, 0, 0, 0);
#elif __has_builtin(__builtin_amdgcn_mfma_f32_16x16x16_bf16)
    return __builtin_amdgcn_mfma_f32_16x16x16_bf16(a, b, c, 0, 0, 0);
#else
    asm("v_mfma_f32_16x16x16_bf16 %0, %1, %2, %0" : "+v"(c) : "v"(a), "v"(b));
    return c;
#endif
}

__device__ __forceinline__ u16 f2bf(float f) {
    union { float f; unsigned u; } v; v.f = f;
    unsigned u = v.u;
    u += 0x7FFFu + ((u >> 16) & 1u);   // RNE
    return (u16)(u >> 16);
}
__device__ __forceinline__ short tbf(float f) {   // truncating fp32->bf16
    union { float f; unsigned u; } v; v.f = f;
    return (short)(v.u >> 16);
}
// exp2 via compiler-known TRANS op (inline-asm v_exp_f32 lacks the TRANS->VALU
// hazard wait states -> corruption; learned round 3). -inf -> 0.
__device__ __forceinline__ float fexp2(float x) {
#if __has_builtin(__builtin_amdgcn_exp2f)
    return __builtin_amdgcn_exp2f(x);
#else
    return exp2f(x);
#endif
}

// async global->LDS, 16B per lane; LDS dest must be wave-uniform base (+lane*16 by HW)
__device__ __forceinline__ void gl_lds16(const void* g, void* s) {
    __builtin_amdgcn_global_load_lds(
        (__attribute__((address_space(1))) void*)g,
        (__attribute__((address_space(3))) void*)s,
        16, 0, 0);
}

// ---------------- stage 1a: x fp32 -> bf16 ----------------
__global__ void cvt_x(const float* __restrict__ x, u16* __restrict__ xb, int n4) {
    int i = blockIdx.x * blockDim.x + threadIdx.x;
    if (i < n4) {
        float4 v = ((const float4*)x)[i];
        ushort4 o;
        o.x = f2bf(v.x); o.y = f2bf(v.y); o.z = f2bf(v.z); o.w = f2bf(v.w);
        ((ushort4*)xb)[i] = o;
    }
}

// ---------------- stage 1b: Wq/Wk/Wv [H][C][HS] fp32 -> WT[z][h*64+d][c] bf16 ----------------
__global__ void transpose_w(const float* __restrict__ Wq, const float* __restrict__ Wk,
                            const float* __restrict__ Wv, u16* __restrict__ WT) {
    __shared__ float tile[64][65];
    const int tid = threadIdx.x;
    const int c0  = blockIdx.x * 64;   // C-tile
    const int h   = blockIdx.y;
    const int z   = blockIdx.z;
    const float* W = (z == 0 ? Wq : (z == 1 ? Wk : Wv)) + (size_t)h * 1024 * 64;
    u16* out = WT + (size_t)z * 1024 * 1024 + (size_t)h * 64 * 1024;
    #pragma unroll
    for (int i = 0; i < 16; ++i) {
        int idx = i * 256 + tid;
        int r = idx >> 6, d = idx & 63;          // read W[c0+r][d], coalesced in d
        tile[d][r] = W[(size_t)(c0 + r) * 64 + d];
    }
    __syncthreads();
    #pragma unroll
    for (int i = 0; i < 16; ++i) {
        int idx = i * 256 + tid;
        int d = idx >> 6, j = idx & 63;          // write out[d][c0+j], coalesced in j
        out[(size_t)d * 1024 + c0 + j] = f2bf(tile[d][j]);
    }
}

// ---------------- stage 1c: Wproj [C][C] fp32 -> WpT[n][c] bf16 ----------------
__global__ void transpose_p(const float* __restrict__ Wp, u16* __restrict__ WpT) {
    __shared__ float tile[64][65];
    const int tid = threadIdx.x;
    const int c0  = blockIdx.x * 64;
    const int n0  = blockIdx.y * 64;
    #pragma unroll
    for (int i = 0; i < 16; ++i) {
        int idx = i * 256 + tid;
        int r = idx >> 6, j = idx & 63;          // Wp[c0+r][n0+j]
        tile[j][r] = Wp[(size_t)(c0 + r) * 1024 + n0 + j];
    }
    __syncthreads();
    #pragma unroll
    for (int i = 0; i < 16; ++i) {
        int idx = i * 256 + tid;
        int r = idx >> 6, j = idx & 63;          // WpT[n0+r][c0+j]
        WpT[(size_t)(n0 + r) * 1024 + c0 + j] = f2bf(tile[r][j]);
    }
}

// ---------------- bf16 GEMM v2: single-barrier double-buffered K-loop ----------------
// C[m][n] = A[m][k] * Bt[n][k]^T. vs the 2-barrier m97 loop: staging is double-
// buffered and each K-step is {sync (drains loads issued a FULL tile ago); issue
// stage(t+1) into buf^1; ds_read+MFMA on buf}. The in-iteration vmcnt(0)-after-issue
// drain is gone -- load latency hides under compute + barrier-wait (same transform
// that took attn 73->~60us this session). WAR-safe: stage(t+1) overwrites the buffer
// last ds_read by compute(t-1), which every wave completed before barrier(t).
// Q scaled by C^-0.5*log2e for exp2-softmax; z==2 V^T epilogue bounces through LDS.
template <int MODE>
__global__ __launch_bounds__(256, 2)
void gemm_bt(const u16* __restrict__ A, const u16* __restrict__ Bt,
             u16* __restrict__ Oq, u16* __restrict__ Ok, u16* __restrict__ Ov,
             float* __restrict__ Op, const float* __restrict__ bias) {
    constexpr int K = 1024;
    constexpr int NT = K / 32;          // 32 K-steps
    __shared__ __align__(16) u16 As[2][128 * 32];   // 16KB (also epilogue bounce buf)
    __shared__ __align__(16) u16 Bs[2][128 * 32];   // 16KB
    const int tid  = threadIdx.x;
    const int w    = tid >> 6;
    const int lane = tid & 63;
    const int quad = lane >> 4;
    const int l16  = lane & 15;
    const int m0   = blockIdx.x * 128;
    const int n0   = blockIdx.y * 128;
    const u16* Bp  = (MODE == 0) ? (Bt + (size_t)blockIdx.z * 1024 * 1024) : Bt;

    const f32x4 zero = {0.f, 0.f, 0.f, 0.f};
    f32x4 acc[4][4];
    #pragma unroll
    for (int i = 0; i < 4; ++i)
        #pragma unroll
        for (int j = 0; j < 4; ++j) acc[i][j] = zero;

    const int wr = (w >> 1) * 64;
    const int wc = (w & 1) * 64;

    // stage one 128x32 tile (8KB): 2 gl_lds per thread; chunk c -> row c>>2, ko (c&3)*8
    auto stage = [&](const u16* G, int gr0, int k0, u16* dst) {
        #pragma unroll
        for (int i = 0; i < 2; ++i) {
            int c = i * 256 + tid;
            int row = c >> 2, ko = (c & 3) * 8;
            gl_lds16(G + (size_t)(gr0 + row) * K + (k0 + ko),
                     dst + (size_t)(i * 256 + w * 64) * 8);
        }
    };

    // prologue: tile 0 into buffer 0
    stage(A,  m0, 0, As[0]);
    stage(Bp, n0, 0, Bs[0]);

    for (int kt = 0; kt < NT; ++kt) {
        __syncthreads();                 // drains gl_lds of tile kt; restage WAR-safe
        if (kt + 1 < NT) {
            stage(A,  m0, (kt + 1) * 32, As[(kt + 1) & 1]);
            stage(Bp, n0, (kt + 1) * 32, Bs[(kt + 1) & 1]);
        }
        const u16* Ac = As[kt & 1];
        const u16* Bc = Bs[kt & 1];
        bf16x8 af[4], bfr[4];
        #pragma unroll
        for (int i = 0; i < 4; ++i)
            af[i] = *(const bf16x8*)&Ac[(wr + i * 16 + l16) * 32 + quad * 8];
        #pragma unroll
        for (int j = 0; j < 4; ++j)
            bfr[j] = *(const bf16x8*)&Bc[(wc + j * 16 + l16) * 32 + quad * 8];
        #pragma unroll
        for (int i = 0; i < 4; ++i)
            #pragma unroll
            for (int j = 0; j < 4; ++j)
                acc[i][j] = MFMA_BF16(af[i], bfr[j], acc[i][j]);
    }

    // epilogue: C/D layout row=(quad*4+r), col=l16 within each 16x16 frag (m89/m91-verified)
    if (MODE == 0 && blockIdx.z == 2) {
        // V^T output: Ov[(bh*64+d)][t] -- bounce through LDS for coalesced stores.
        u32* buf = (u32*)As;             // 16KB = 128*32 u32, exact fit
        const int bh0 = (m0 >> 11) * 16;
        #pragma unroll
        for (int mh = 0; mh < 2; ++mh) {
            __syncthreads();           // K-loop reads / previous pass reads done
            if ((w >> 1) == mh) {
                #pragma unroll
                for (int i = 0; i < 4; ++i)
                    #pragma unroll
                    for (int j = 0; j < 4; ++j)
                        #pragma unroll
                        for (int rp = 0; rp < 2; ++rp) {
                            const int nl = wc + j * 16 + l16;       // 0..127
                            const int t2 = i * 8 + quad * 2 + rp;   // t-pair idx in pass
                            const u32 lo = f2bf(acc[i][j][2 * rp]);
                            const u32 hi = f2bf(acc[i][j][2 * rp + 1]);
                            buf[nl * 32 + (t2 ^ ((nl & 7) << 2))] = lo | (hi << 16);
                        }
            }
            __syncthreads();
            const int nl = tid >> 1, half = tid & 1;
            const int h = (n0 + nl) >> 6, d = (n0 + nl) & 63;
            u16* orow = Ov + ((size_t)(bh0 + h) * 64 + d) * 2048 + (m0 & 2047) + mh * 64;
            #pragma unroll
            for (int c = 0; c < 4; ++c) {
                const int d2b = half * 16 + c * 4;
                uint4 vv = *(const uint4*)&buf[nl * 32 + (d2b ^ ((nl & 7) << 2))];
                *(uint4*)(orow + d2b * 2) = vv;
            }
        }
    } else {
        #pragma unroll
        for (int i = 0; i < 4; ++i) {
            #pragma unroll
            for (int j = 0; j < 4; ++j) {
                #pragma unroll
                for (int r = 0; r < 4; ++r) {
                    const int m = m0 + wr + i * 16 + quad * 4 + r;
                    const int n = n0 + wc + j * 16 + l16;
                    const float v = acc[i][j][r];
                    if (MODE == 0) {
                        const int b = m >> 11, t = m & 2047;
                        const int h = n >> 6, d = n & 63;
                        const int bh = b * 16 + h;
                        if (blockIdx.z == 0)   // scale C^-0.5 * log2(e) for exp2-softmax
                            Oq[((size_t)bh * 2048 + t) * 64 + d] = f2bf(v * 0.0450842203f);
                        else
                            Ok[((size_t)bh * 2048 + t) * 64 + d] = f2bf(v);
                    } else {
                        Op[(size_t)m * 1024 + n] = v + bias[n];
                    }
                }
            }
        }
    }
}

// ---------------- flash attention v10: single-barrier gl_lds pipeline ----------------
// (passing, ~60us) V staged via global_load_lds into linear [64][128] with row-XOR
// swizzle on the GLOBAL SOURCE; one barrier per K-iter; K tiles 4-slot XOR-swizzled.
// Grid: (8,64) with the BALANCED fwd/rev tile pairing (every block = 17 K-iters).
// Q,K: [bh][T][64] bf16 (Q pre-scaled); Vt: [bh][64][T]; O -> Xo [b*T][1024] bf16.
__global__ __launch_bounds__(256, 2)
void attn10(const u16* __restrict__ Q, const u16* __restrict__ Kg,
            const u16* __restrict__ Vt, u16* __restrict__ O) {
    __shared__ __align__(16) u16 Ks[2][2 * 128 * 32];  // double-buffered K  32KB
    __shared__ __align__(16) u16 Vs[2][64 * 128];      // double-buffered V  32KB (+O-bounce)
    const int tid  = threadIdx.x;
    const int w    = tid >> 6;          // 0..3
    const int lane = tid & 63;
    const int quad = lane >> 4;
    const int l16  = lane & 15;
    const int bh   = blockIdx.y;
    const u16* Qp = Q  + (size_t)bh * 2048 * 64;
    const u16* Kp = Kg + (size_t)bh * 2048 * 64;
    const u16* Vp = Vt + (size_t)bh * 64 * 2048;
    const int b = bh >> 4, h = bh & 15;
    const float NEG_INF = -__builtin_inff();
    const f32x4 zero = {0.f, 0.f, 0.f, 0.f};
    const short ONE = (short)0x3F80;    // bf16 1.0
    const bf16x4 vones = {ONE, ONE, ONE, ONE};
    const int ksw = ((l16 >> 1) & 3) << 3;   // read-side K swizzle (u16 units, 4-slot)

    // stage one 128x64 K tile (16KB): 16 wave-instrs; chunk-in-row XOR (row>>1)&3
    auto stageK = [&](int sb, u16* dst) {
        #pragma unroll
        for (int i = 0; i < 4; ++i) {
            int c = i * 256 + tid;
            int kk = c >> 9, row = (c >> 2) & 127;
            int q4s = (c & 3) ^ ((row >> 1) & 3);
            gl_lds16(Kp + (size_t)(sb + row) * 64 + kk * 32 + q4s * 8,
                     dst + (size_t)(i * 256 + w * 64) * 8);
        }
    };
    // stage one 64x128 V^T tile (16KB) into linear [64][128] with row-XOR swizzle:
    // phys 16B-chunk (d, ci) holds logical (d, ci ^ (d&7)); inverse applied on source.
    auto stageV = [&](int sb, u16* dst) {
        #pragma unroll
        for (int i = 0; i < 4; ++i) {
            int j = 4 * w + i;               // 16 instrs, 4 rows each
            int d = j * 4 + quad;
            int ci = l16 ^ (d & 7);
            gl_lds16(Vp + (size_t)d * 2048 + sb + ci * 8, dst + (size_t)j * 512);
        }
    };
    // PV A-frag read: V^T[d][s..s+3] from swizzled Vs (8B-aligned, 2-way banks = free)
    auto ldv = [&](const u16* Vc, int d, int s) -> bf16x4 {
        int off  = d * 128 + s;
        int phys = (off & 7) | (((off >> 3) ^ (d & 7)) << 3);
        return *(const bf16x4*)&Vc[phys];
    };

    #pragma unroll
    for (int ph = 0; ph < 2; ++ph) {
        const int tt = ph ? (int)blockIdx.x : 15 - (int)blockIdx.x;
        const int t0 = tt * 128;
        const int ns = tt + 1;

        // Q B-frags for this phase's 32 t-rows per wave
        bf16x8 bq[2][2];
        #pragma unroll
        for (int tf = 0; tf < 2; ++tf)
            #pragma unroll
            for (int kk = 0; kk < 2; ++kk)
                bq[tf][kk] = *(const bf16x8*)(Qp + (size_t)(t0 + w * 32 + tf * 16 + l16) * 64
                                              + kk * 32 + quad * 8);

        f32x4 oacc[4][2];
        f32x4 lacc[2] = {zero, zero};   // ones-MFMA softmax denominator, per tf
        #pragma unroll
        for (int df = 0; df < 4; ++df)
            #pragma unroll
            for (int tf = 0; tf < 2; ++tf) oacc[df][tf] = zero;

        __syncthreads();                 // prior phase's LDS reads (incl. O-bounce) done
        stageK(0, Ks[0]);
        stageV(0, Vs[0]);

        for (int it = 0; it < ns; ++it) {
            const int s0 = it * 128;
            __syncthreads();             // drains gl_lds(it) [vmcnt0 in syncthreads];
                                         // all waves past compute(it-1) -> restage safe
            if (it + 1 < ns) {
                stageK(s0 + 128, Ks[(it + 1) & 1]);
                stageV(s0 + 128, Vs[(it + 1) & 1]);
            }

            // ---- compute tile it ----
            const u16* Kc = Ks[it & 1];
            const u16* Vc = Vs[it & 1];
            const bool diag = (it == ns - 1);
            bf16x4 bp[8][2];
            #pragma unroll
            for (int st = 0; st < 8; ++st) {
                const int kbase = (st * 16 + l16) * 32 + quad * 8;
                bf16x8 ak0 = *(const bf16x8*)&Kc[kbase ^ ksw];
                bf16x8 ak1 = *(const bf16x8*)&Kc[(128 * 32) + (kbase ^ ksw)];
                #pragma unroll
                for (int tf = 0; tf < 2; ++tf) {
                    f32x4 s = MFMA_BF16(ak0, bq[tf][0], zero);
                    s = MFMA_BF16(ak1, bq[tf][1], s);
                    if (diag) {
                        #pragma unroll
                        for (int r = 0; r < 4; ++r) {
                            int ss = s0 + st * 16 + quad * 4 + r;
                            int t  = t0 + w * 32 + tf * 16 + l16;
                            if (ss > t) s[r] = NEG_INF;
                        }
                    }
                    float p0 = fexp2(s[0]), p1 = fexp2(s[1]);
                    float p2 = fexp2(s[2]), p3 = fexp2(s[3]);
                    bf16x4 bb; bb[0] = tbf(p0); bb[1] = tbf(p1);
                    bb[2] = tbf(p2); bb[3] = tbf(p3);
                    bp[st][tf] = bb;
                }
            }
            // denominator: lacc[tf][*] += ones . P
            #pragma unroll
            for (int st = 0; st < 8; ++st)
                #pragma unroll
                for (int tf = 0; tf < 2; ++tf)
                    lacc[tf] = mfma16(vones, bp[st][tf], lacc[tf]);
            // O^T += V^T P^T : A-frags from swizzled Vs, B = bp (regs)
            #pragma unroll
            for (int kcp = 0; kcp < 4; ++kcp)
                #pragma unroll
                for (int df = 0; df < 4; ++df) {
                    const int d = df * 16 + l16;
                    bf16x4 alo = ldv(Vc, d, kcp * 32 + quad * 4);
                    bf16x4 ahi = ldv(Vc, d, kcp * 32 + 16 + quad * 4);
                    #pragma unroll
                    for (int tf = 0; tf < 2; ++tf) {
                        oacc[df][tf] = mfma16(alo, bp[2 * kcp][tf], oacc[df][tf]);
                        oacc[df][tf] = mfma16(ahi, bp[2 * kcp + 1][tf], oacc[df][tf]);
                    }
                }
        }

        // epilogue: bounce O-tile [t 128][d 64] through Vs, store coalesced dwordx4.
        __syncthreads();                 // all waves done reading Ks/Vs this phase
        {
            u32* ob = (u32*)Vs;
            const float inv[2] = {1.0f / lacc[0][0], 1.0f / lacc[1][0]};
            #pragma unroll
            for (int df = 0; df < 4; ++df)
                #pragma unroll
                for (int tf = 0; tf < 2; ++tf) {
                    const int tl = w * 32 + tf * 16 + l16;
                    #pragma unroll
                    for (int rp = 0; rp < 2; ++rp) {
                        const u32 lo = f2bf(oacc[df][tf][2 * rp]     * inv[tf]);
                        const u32 hi = f2bf(oacc[df][tf][2 * rp + 1] * inv[tf]);
                        const int d2 = df * 8 + quad * 2 + rp;
                        ob[tl * 32 + (d2 ^ ((tl & 7) << 2))] = lo | (hi << 16);
                    }
                }
            __syncthreads();
            const int tl = tid >> 1, half = tid & 1;
            u16* orow = O + ((size_t)(b * 2048 + t0 + tl)) * 1024 + h * 64;
            #pragma unroll
            for (int c = 0; c < 4; ++c) {
                const int d2b = half * 16 + c * 4;
                uint4 vv = *(const uint4*)&ob[tl * 32 + (d2b ^ ((tl & 7) << 2))];
                *(uint4*)(orow + d2b * 2) = vv;
            }
        }
    }
}

extern "C" void kernel_launch(void* const* d_in, const int* in_sizes, int n_in,
                              void* d_out, int out_size, void* d_ws, size_t ws_size,
                              hipStream_t stream) {
    const float* x  = (const float*)d_in[0];
    const float* Wq = (const float*)d_in[1];
    const float* Wk = (const float*)d_in[2];
    const float* Wv = (const float*)d_in[3];
    const float* Wp = (const float*)d_in[4];
    const float* bp = (const float*)d_in[5];
    float* out = (float*)d_out;

    char* ws = (char*)d_ws;
    // layout (bytes): Xb/Xo share region 0 (Xb dead before attn writes Xo)
    u16* Xb  = (u16*)(ws);                          // [8192][1024] bf16 (16 MB)
    u16* Xo  = (u16*)(ws);                          // attn output, same region
    u16* WT  = (u16*)(ws + (16ull << 20));          // 3 x [1024][1024] (6 MB)
    u16* WpT = (u16*)(ws + (22ull << 20));          // [1024][1024] (2 MB)
    u16* Qw  = (u16*)(ws + (24ull << 20));          // [64][2048][64] (16 MB)
    u16* Kw  = (u16*)(ws + (40ull << 20));          // [64][2048][64] (16 MB)
    u16* Vw  = (u16*)(ws + (56ull << 20));          // [64][64][2048] (16 MB)
    // total 72 MB

    cvt_x<<<8192, 256, 0, stream>>>(x, Xb, 8192 * 1024 / 4);
    transpose_w<<<dim3(16, 16, 3), 256, 0, stream>>>(Wq, Wk, Wv, WT);
    transpose_p<<<dim3(16, 16), 256, 0, stream>>>(Wp, WpT);
    gemm_bt<0><<<dim3(64, 8, 3), 256, 0, stream>>>(Xb, WT, Qw, Kw, Vw, nullptr, nullptr);
    attn10<<<dim3(8, 64), 256, 0, stream>>>(Qw, Kw, Vw, Xo);
    gemm_bt<1><<<dim3(64, 8, 1), 256, 0, stream>>>(Xo, WpT, nullptr, nullptr, nullptr, out, bp);
}

// Round 8
// 247.382 us; speedup vs baseline: 1.0261x; 1.0261x over previous
//
#include <hip/hip_runtime.h>

// MultiHeadAttention: B=4, T=2048, C=1024, H=16, HS=64
// out = softmax(causal((x@Wq)(x@Wk)^T * C^-0.5)) (x@Wv)  -> concat -> @Wproj + bproj

using u16    = unsigned short;
using u32    = unsigned int;
using bf16x8 = __attribute__((ext_vector_type(8))) short;  // 8 bf16 (4 VGPRs)
using bf16x4 = __attribute__((ext_vector_type(4))) short;  // 4 bf16 (2 VGPRs)
using f32x4  = __attribute__((ext_vector_type(4))) float;  // MFMA 16x16 C/D

#define MFMA_BF16(a, b, c) __builtin_amdgcn_mfma_f32_16x16x32_bf16((a), (b), (c), 0, 0, 0)

// K=16 bf16 MFMA (v_mfma_f32_16x16x16_bf16): A/B = 4 bf16 (2 VGPRs), C/D = 4 f32
__device__ __forceinline__ f32x4 mfma16(bf16x4 a, bf16x4 b, f32x4 c) {
#if __has_builtin(__builtin_amdgcn_mfma_f32_16x16x16bf16_1k)
    return __builtin_amdgcn_mfma_f32_16x16x16bf16_1k(a, b, c, 0, 0, 0);
#elif __has_builtin(__builtin_amdgcn_mfma_f32_16x16x16_bf16)
    return __builtin_amdgcn_mfma_f32_16x16x16_bf16(a, b, c, 0, 0, 0);
#else
    asm("v_mfma_f32_16x16x16_bf16 %0, %1, %2, %0" : "+v"(c) : "v"(a), "v"(b));
    return c;
#endif
}

__device__ __forceinline__ u16 f2bf(float f) {
    union { float f; unsigned u; } v; v.f = f;
    unsigned u = v.u;
    u += 0x7FFFu + ((u >> 16) & 1u);   // RNE
    return (u16)(u >> 16);
}
__device__ __forceinline__ short tbf(float f) {   // truncating fp32->bf16
    union { float f; unsigned u; } v; v.f = f;
    return (short)(v.u >> 16);
}
// exp2 via compiler-known TRANS op (inline-asm v_exp_f32 lacks the TRANS->VALU
// hazard wait states -> corruption; learned round 3). -inf -> 0.
__device__ __forceinline__ float fexp2(float x) {
#if __has_builtin(__builtin_amdgcn_exp2f)
    return __builtin_amdgcn_exp2f(x);
#else
    return exp2f(x);
#endif
}

// async global->LDS, 16B per lane; LDS dest must be wave-uniform base (+lane*16 by HW)
__device__ __forceinline__ void gl_lds16(const void* g, void* s) {
    __builtin_amdgcn_global_load_lds(
        (__attribute__((address_space(1))) void*)g,
        (__attribute__((address_space(3))) void*)s,
        16, 0, 0);
}

// ---------------- stage 1a: x fp32 -> bf16 ----------------
__global__ void cvt_x(const float* __restrict__ x, u16* __restrict__ xb, int n4) {
    int i = blockIdx.x * blockDim.x + threadIdx.x;
    if (i < n4) {
        float4 v = ((const float4*)x)[i];
        ushort4 o;
        o.x = f2bf(v.x); o.y = f2bf(v.y); o.z = f2bf(v.z); o.w = f2bf(v.w);
        ((ushort4*)xb)[i] = o;
    }
}

// ---------------- stage 1b: Wq/Wk/Wv [H][C][HS] fp32 -> WT[z][h*64+d][c] bf16 ----------------
__global__ void transpose_w(const float* __restrict__ Wq, const float* __restrict__ Wk,
                            const float* __restrict__ Wv, u16* __restrict__ WT) {
    __shared__ float tile[64][65];
    const int tid = threadIdx.x;
    const int c0  = blockIdx.x * 64;   // C-tile
    const int h   = blockIdx.y;
    const int z   = blockIdx.z;
    const float* W = (z == 0 ? Wq : (z == 1 ? Wk : Wv)) + (size_t)h * 1024 * 64;
    u16* out = WT + (size_t)z * 1024 * 1024 + (size_t)h * 64 * 1024;
    #pragma unroll
    for (int i = 0; i < 16; ++i) {
        int idx = i * 256 + tid;
        int r = idx >> 6, d = idx & 63;          // read W[c0+r][d], coalesced in d
        tile[d][r] = W[(size_t)(c0 + r) * 64 + d];
    }
    __syncthreads();
    #pragma unroll
    for (int i = 0; i < 16; ++i) {
        int idx = i * 256 + tid;
        int d = idx >> 6, j = idx & 63;          // write out[d][c0+j], coalesced in j
        out[(size_t)d * 1024 + c0 + j] = f2bf(tile[d][j]);
    }
}

// ---------------- stage 1c: Wproj [C][C] fp32 -> WpT[n][c] bf16 ----------------
__global__ void transpose_p(const float* __restrict__ Wp, u16* __restrict__ WpT) {
    __shared__ float tile[64][65];
    const int tid = threadIdx.x;
    const int c0  = blockIdx.x * 64;
    const int n0  = blockIdx.y * 64;
    #pragma unroll
    for (int i = 0; i < 16; ++i) {
        int idx = i * 256 + tid;
        int r = idx >> 6, j = idx & 63;          // Wp[c0+r][n0+j]
        tile[j][r] = Wp[(size_t)(c0 + r) * 1024 + n0 + j];
    }
    __syncthreads();
    #pragma unroll
    for (int i = 0; i < 16; ++i) {
        int idx = i * 256 + tid;
        int r = idx >> 6, j = idx & 63;          // WpT[n0+r][c0+j]
        WpT[(size_t)(n0 + r) * 1024 + c0 + j] = f2bf(tile[r][j]);
    }
}

// ---------------- m97-style bf16 GEMM: C[m][n] = A[m][k] * Bt[n][k]^T ----------------
// (proven structure -- round-6 best config. Single-barrier dbuf tried in round 7:
//  NEUTRAL (72.2 -> 72.3us); at 2 blocks/CU the other block's waves already fill the
//  drain stall, matching the documented m99/m100 null. Kept 2-barrier 16KB version.)
// Q scaled by C^-0.5*log2e for exp2-softmax; z==2 V^T epilogue bounces through LDS.
template <int MODE>
__global__ __launch_bounds__(256, 2)
void gemm_bt(const u16* __restrict__ A, const u16* __restrict__ Bt,
             u16* __restrict__ Oq, u16* __restrict__ Ok, u16* __restrict__ Ov,
             float* __restrict__ Op, const float* __restrict__ bias) {
    constexpr int K = 1024;
    __shared__ u16 SH[2][128 * 32];     // SH[0]=As, SH[1]=Bs (adjacent: reused as bounce buf)
    u16* As = SH[0];
    u16* Bs = SH[1];
    const int tid  = threadIdx.x;
    const int w    = tid >> 6;
    const int lane = tid & 63;
    const int quad = lane >> 4;
    const int l16  = lane & 15;
    const int m0   = blockIdx.x * 128;
    const int n0   = blockIdx.y * 128;
    const u16* Bp  = (MODE == 0) ? (Bt + (size_t)blockIdx.z * 1024 * 1024) : Bt;

    const f32x4 zero = {0.f, 0.f, 0.f, 0.f};
    f32x4 acc[4][4];
    #pragma unroll
    for (int i = 0; i < 4; ++i)
        #pragma unroll
        for (int j = 0; j < 4; ++j) acc[i][j] = zero;

    const int wr = (w >> 1) * 64;
    const int wc = (w & 1) * 64;

    for (int k0 = 0; k0 < K; k0 += 32) {
        __syncthreads();
        #pragma unroll
        for (int i = 0; i < 2; ++i) {
            int c = i * 256 + tid;                 // chunk id, 512 x 16B = 8KB tile
            int row = c >> 2, ko = (c & 3) * 8;
            gl_lds16(A + (size_t)(m0 + row) * K + (k0 + ko), &As[(i * 256 + w * 64) * 8]);
        }
        #pragma unroll
        for (int i = 0; i < 2; ++i) {
            int c = i * 256 + tid;
            int row = c >> 2, ko = (c & 3) * 8;
            gl_lds16(Bp + (size_t)(n0 + row) * K + (k0 + ko), &Bs[(i * 256 + w * 64) * 8]);
        }
        __syncthreads();
        bf16x8 af[4], bfr[4];
        #pragma unroll
        for (int i = 0; i < 4; ++i)
            af[i] = *(const bf16x8*)&As[(wr + i * 16 + l16) * 32 + quad * 8];
        #pragma unroll
        for (int j = 0; j < 4; ++j)
            bfr[j] = *(const bf16x8*)&Bs[(wc + j * 16 + l16) * 32 + quad * 8];
        #pragma unroll
        for (int i = 0; i < 4; ++i)
            #pragma unroll
            for (int j = 0; j < 4; ++j)
                acc[i][j] = MFMA_BF16(af[i], bfr[j], acc[i][j]);
    }

    // epilogue: C/D layout row=(quad*4+r), col=l16 within each 16x16 frag (m89/m91-verified)
    if (MODE == 0 && blockIdx.z == 2) {
        // V^T output: Ov[(bh*64+d)][t] -- bounce through LDS for coalesced stores.
        u32* buf = (u32*)SH;
        const int bh0 = (m0 >> 11) * 16;
        #pragma unroll
        for (int mh = 0; mh < 2; ++mh) {
            __syncthreads();           // K-loop reads / previous pass reads done
            if ((w >> 1) == mh) {
                #pragma unroll
                for (int i = 0; i < 4; ++i)
                    #pragma unroll
                    for (int j = 0; j < 4; ++j)
                        #pragma unroll
                        for (int rp = 0; rp < 2; ++rp) {
                            const int nl = wc + j * 16 + l16;       // 0..127
                            const int t2 = i * 8 + quad * 2 + rp;   // t-pair idx in pass
                            const u32 lo = f2bf(acc[i][j][2 * rp]);
                            const u32 hi = f2bf(acc[i][j][2 * rp + 1]);
                            buf[nl * 32 + (t2 ^ ((nl & 7) << 2))] = lo | (hi << 16);
                        }
            }
            __syncthreads();
            const int nl = tid >> 1, half = tid & 1;
            const int h = (n0 + nl) >> 6, d = (n0 + nl) & 63;
            u16* orow = Ov + ((size_t)(bh0 + h) * 64 + d) * 2048 + (m0 & 2047) + mh * 64;
            #pragma unroll
            for (int c = 0; c < 4; ++c) {
                const int d2b = half * 16 + c * 4;
                uint4 vv = *(const uint4*)&buf[nl * 32 + (d2b ^ ((nl & 7) << 2))];
                *(uint4*)(orow + d2b * 2) = vv;
            }
        }
    } else {
        #pragma unroll
        for (int i = 0; i < 4; ++i) {
            #pragma unroll
            for (int j = 0; j < 4; ++j) {
                #pragma unroll
                for (int r = 0; r < 4; ++r) {
                    const int m = m0 + wr + i * 16 + quad * 4 + r;
                    const int n = n0 + wc + j * 16 + l16;
                    const float v = acc[i][j][r];
                    if (MODE == 0) {
                        const int b = m >> 11, t = m & 2047;
                        const int h = n >> 6, d = n & 63;
                        const int bh = b * 16 + h;
                        if (blockIdx.z == 0)   // scale C^-0.5 * log2(e) for exp2-softmax
                            Oq[((size_t)bh * 2048 + t) * 64 + d] = f2bf(v * 0.0450842203f);
                        else
                            Ok[((size_t)bh * 2048 + t) * 64 + d] = f2bf(v);
                    } else {
                        Op[(size_t)m * 1024 + n] = v + bias[n];
                    }
                }
            }
        }
    }
}

// ---------------- flash attention v11: XCD-local K/V mapping ----------------
// vs v10 (best): grid swapped to dim3(64 bh, 8 xi). Under round-robin workgroup->XCD
// (XCD = flat_id % 8, flat = x + 64*y => XCD = bh % 8), each XCD now serves 8 bh
// whose K/V total 8 x 512KB = 4MB = one L2 -- and all 8 blocks sharing a bh's K/V
// are co-resident on ONE XCD. Old mapping put each bh's 8 blocks on 8 DIFFERENT
// XCDs (FETCH_SIZE 147MB vs 48MB working set). Work balance unchanged: every block
// still runs the fwd/rev tile pairing (17 K-iters).
// V staged via global_load_lds into linear [64][128] with row-XOR swizzle on the
// GLOBAL SOURCE; one barrier per K-iter; K tiles 4-slot XOR-swizzled.
// Q,K: [bh][T][64] bf16 (Q pre-scaled); Vt: [bh][64][T]; O -> Xo [b*T][1024] bf16.
__global__ __launch_bounds__(256, 2)
void attn11(const u16* __restrict__ Q, const u16* __restrict__ Kg,
            const u16* __restrict__ Vt, u16* __restrict__ O) {
    __shared__ __align__(16) u16 Ks[2][2 * 128 * 32];  // double-buffered K  32KB
    __shared__ __align__(16) u16 Vs[2][64 * 128];      // double-buffered V  32KB (+O-bounce)
    const int tid  = threadIdx.x;
    const int w    = tid >> 6;          // 0..3
    const int lane = tid & 63;
    const int quad = lane >> 4;
    const int l16  = lane & 15;
    const int bh   = blockIdx.x;        // XCD = bh % 8 under round-robin
    const int xi   = blockIdx.y;
    const u16* Qp = Q  + (size_t)bh * 2048 * 64;
    const u16* Kp = Kg + (size_t)bh * 2048 * 64;
    const u16* Vp = Vt + (size_t)bh * 64 * 2048;
    const int b = bh >> 4, h = bh & 15;
    const float NEG_INF = -__builtin_inff();
    const f32x4 zero = {0.f, 0.f, 0.f, 0.f};
    const short ONE = (short)0x3F80;    // bf16 1.0
    const bf16x4 vones = {ONE, ONE, ONE, ONE};
    const int ksw = ((l16 >> 1) & 3) << 3;   // read-side K swizzle (u16 units, 4-slot)

    // stage one 128x64 K tile (16KB): 16 wave-instrs; chunk-in-row XOR (row>>1)&3
    auto stageK = [&](int sb, u16* dst) {
        #pragma unroll
        for (int i = 0; i < 4; ++i) {
            int c = i * 256 + tid;
            int kk = c >> 9, row = (c >> 2) & 127;
            int q4s = (c & 3) ^ ((row >> 1) & 3);
            gl_lds16(Kp + (size_t)(sb + row) * 64 + kk * 32 + q4s * 8,
                     dst + (size_t)(i * 256 + w * 64) * 8);
        }
    };
    // stage one 64x128 V^T tile (16KB) into linear [64][128] with row-XOR swizzle:
    // phys 16B-chunk (d, ci) holds logical (d, ci ^ (d&7)); inverse applied on source.
    auto stageV = [&](int sb, u16* dst) {
        #pragma unroll
        for (int i = 0; i < 4; ++i) {
            int j = 4 * w + i;               // 16 instrs, 4 rows each
            int d = j * 4 + quad;
            int ci = l16 ^ (d & 7);
            gl_lds16(Vp + (size_t)d * 2048 + sb + ci * 8, dst + (size_t)j * 512);
        }
    };
    // PV A-frag read: V^T[d][s..s+3] from swizzled Vs (8B-aligned, 2-way banks = free)
    auto ldv = [&](const u16* Vc, int d, int s) -> bf16x4 {
        int off  = d * 128 + s;
        int phys = (off & 7) | (((off >> 3) ^ (d & 7)) << 3);
        return *(const bf16x4*)&Vc[phys];
    };

    #pragma unroll
    for (int ph = 0; ph < 2; ++ph) {
        const int tt = ph ? xi : 15 - xi;
        const int t0 = tt * 128;
        const int ns = tt + 1;

        // Q B-frags for this phase's 32 t-rows per wave
        bf16x8 bq[2][2];
        #pragma unroll
        for (int tf = 0; tf < 2; ++tf)
            #pragma unroll
            for (int kk = 0; kk < 2; ++kk)
                bq[tf][kk] = *(const bf16x8*)(Qp + (size_t)(t0 + w * 32 + tf * 16 + l16) * 64
                                              + kk * 32 + quad * 8);

        f32x4 oacc[4][2];
        f32x4 lacc[2] = {zero, zero};   // ones-MFMA softmax denominator, per tf
        #pragma unroll
        for (int df = 0; df < 4; ++df)
            #pragma unroll
            for (int tf = 0; tf < 2; ++tf) oacc[df][tf] = zero;

        __syncthreads();                 // prior phase's LDS reads (incl. O-bounce) done
        stageK(0, Ks[0]);
        stageV(0, Vs[0]);

        for (int it = 0; it < ns; ++it) {
            const int s0 = it * 128;
            __syncthreads();             // drains gl_lds(it) [vmcnt0 in syncthreads];
                                         // all waves past compute(it-1) -> restage safe
            if (it + 1 < ns) {
                stageK(s0 + 128, Ks[(it + 1) & 1]);
                stageV(s0 + 128, Vs[(it + 1) & 1]);
            }

            // ---- compute tile it ----
            const u16* Kc = Ks[it & 1];
            const u16* Vc = Vs[it & 1];
            const bool diag = (it == ns - 1);
            bf16x4 bp[8][2];
            #pragma unroll
            for (int st = 0; st < 8; ++st) {
                const int kbase = (st * 16 + l16) * 32 + quad * 8;
                bf16x8 ak0 = *(const bf16x8*)&Kc[kbase ^ ksw];
                bf16x8 ak1 = *(const bf16x8*)&Kc[(128 * 32) + (kbase ^ ksw)];
                #pragma unroll
                for (int tf = 0; tf < 2; ++tf) {
                    f32x4 s = MFMA_BF16(ak0, bq[tf][0], zero);
                    s = MFMA_BF16(ak1, bq[tf][1], s);
                    if (diag) {
                        #pragma unroll
                        for (int r = 0; r < 4; ++r) {
                            int ss = s0 + st * 16 + quad * 4 + r;
                            int t  = t0 + w * 32 + tf * 16 + l16;
                            if (ss > t) s[r] = NEG_INF;
                        }
                    }
                    float p0 = fexp2(s[0]), p1 = fexp2(s[1]);
                    float p2 = fexp2(s[2]), p3 = fexp2(s[3]);
                    bf16x4 bb; bb[0] = tbf(p0); bb[1] = tbf(p1);
                    bb[2] = tbf(p2); bb[3] = tbf(p3);
                    bp[st][tf] = bb;
                }
            }
            // denominator: lacc[tf][*] += ones . P
            #pragma unroll
            for (int st = 0; st < 8; ++st)
                #pragma unroll
                for (int tf = 0; tf < 2; ++tf)
                    lacc[tf] = mfma16(vones, bp[st][tf], lacc[tf]);
            // O^T += V^T P^T : A-frags from swizzled Vs, B = bp (regs)
            #pragma unroll
            for (int kcp = 0; kcp < 4; ++kcp)
                #pragma unroll
                for (int df = 0; df < 4; ++df) {
                    const int d = df * 16 + l16;
                    bf16x4 alo = ldv(Vc, d, kcp * 32 + quad * 4);
                    bf16x4 ahi = ldv(Vc, d, kcp * 32 + 16 + quad * 4);
                    #pragma unroll
                    for (int tf = 0; tf < 2; ++tf) {
                        oacc[df][tf] = mfma16(alo, bp[2 * kcp][tf], oacc[df][tf]);
                        oacc[df][tf] = mfma16(ahi, bp[2 * kcp + 1][tf], oacc[df][tf]);
                    }
                }
        }

        // epilogue: bounce O-tile [t 128][d 64] through Vs, store coalesced dwordx4.
        __syncthreads();                 // all waves done reading Ks/Vs this phase
        {
            u32* ob = (u32*)Vs;
            const float inv[2] = {1.0f / lacc[0][0], 1.0f / lacc[1][0]};
            #pragma unroll
            for (int df = 0; df < 4; ++df)
                #pragma unroll
                for (int tf = 0; tf < 2; ++tf) {
                    const int tl = w * 32 + tf * 16 + l16;
                    #pragma unroll
                    for (int rp = 0; rp < 2; ++rp) {
                        const u32 lo = f2bf(oacc[df][tf][2 * rp]     * inv[tf]);
                        const u32 hi = f2bf(oacc[df][tf][2 * rp + 1] * inv[tf]);
                        const int d2 = df * 8 + quad * 2 + rp;
                        ob[tl * 32 + (d2 ^ ((tl & 7) << 2))] = lo | (hi << 16);
                    }
                }
            __syncthreads();
            const int tl = tid >> 1, half = tid & 1;
            u16* orow = O + ((size_t)(b * 2048 + t0 + tl)) * 1024 + h * 64;
            #pragma unroll
            for (int c = 0; c < 4; ++c) {
                const int d2b = half * 16 + c * 4;
                uint4 vv = *(const uint4*)&ob[tl * 32 + (d2b ^ ((tl & 7) << 2))];
                *(uint4*)(orow + d2b * 2) = vv;
            }
        }
    }
}

extern "C" void kernel_launch(void* const* d_in, const int* in_sizes, int n_in,
                              void* d_out, int out_size, void* d_ws, size_t ws_size,
                              hipStream_t stream) {
    const float* x  = (const float*)d_in[0];
    const float* Wq = (const float*)d_in[1];
    const float* Wk = (const float*)d_in[2];
    const float* Wv = (const float*)d_in[3];
    const float* Wp = (const float*)d_in[4];
    const float* bp = (const float*)d_in[5];
    float* out = (float*)d_out;

    char* ws = (char*)d_ws;
    // layout (bytes): Xb/Xo share region 0 (Xb dead before attn writes Xo)
    u16* Xb  = (u16*)(ws);                          // [8192][1024] bf16 (16 MB)
    u16* Xo  = (u16*)(ws);                          // attn output, same region
    u16* WT  = (u16*)(ws + (16ull << 20));          // 3 x [1024][1024] (6 MB)
    u16* WpT = (u16*)(ws + (22ull << 20));          // [1024][1024] (2 MB)
    u16* Qw  = (u16*)(ws + (24ull << 20));          // [64][2048][64] (16 MB)
    u16* Kw  = (u16*)(ws + (40ull << 20));          // [64][2048][64] (16 MB)
    u16* Vw  = (u16*)(ws + (56ull << 20));          // [64][64][2048] (16 MB)
    // total 72 MB

    cvt_x<<<8192, 256, 0, stream>>>(x, Xb, 8192 * 1024 / 4);
    transpose_w<<<dim3(16, 16, 3), 256, 0, stream>>>(Wq, Wk, Wv, WT);
    transpose_p<<<dim3(16, 16), 256, 0, stream>>>(Wp, WpT);
    gemm_bt<0><<<dim3(64, 8, 3), 256, 0, stream>>>(Xb, WT, Qw, Kw, Vw, nullptr, nullptr);
    attn11<<<dim3(64, 8), 256, 0, stream>>>(Qw, Kw, Vw, Xo);
    gemm_bt<1><<<dim3(64, 8, 1), 256, 0, stream>>>(Xo, WpT, nullptr, nullptr, nullptr, out, bp);
}

// Round 9
// 228.971 us; speedup vs baseline: 1.1086x; 1.0804x over previous
//
#include <hip/hip_runtime.h>

// MultiHeadAttention: B=4, T=2048, C=1024, H=16, HS=64
// out = softmax(causal((x@Wq)(x@Wk)^T * C^-0.5)) (x@Wv)  -> concat -> @Wproj + bproj

using u16    = unsigned short;
using u32    = unsigned int;
using bf16x8 = __attribute__((ext_vector_type(8))) short;  // 8 bf16 (4 VGPRs)
using bf16x4 = __attribute__((ext_vector_type(4))) short;  // 4 bf16 (2 VGPRs)
using f32x4  = __attribute__((ext_vector_type(4))) float;  // MFMA 16x16 C/D

#define MFMA_BF16(a, b, c) __builtin_amdgcn_mfma_f32_16x16x32_bf16((a), (b), (c), 0, 0, 0)

// K=16 bf16 MFMA (v_mfma_f32_16x16x16_bf16): A/B = 4 bf16 (2 VGPRs), C/D = 4 f32
__device__ __forceinline__ f32x4 mfma16(bf16x4 a, bf16x4 b, f32x4 c) {
#if __has_builtin(__builtin_amdgcn_mfma_f32_16x16x16bf16_1k)
    return __builtin_amdgcn_mfma_f32_16x16x16bf16_1k(a, b, c, 0, 0, 0);
#elif __has_builtin(__builtin_amdgcn_mfma_f32_16x16x16_bf16)
    return __builtin_amdgcn_mfma_f32_16x16x16_bf16(a, b, c, 0, 0, 0);
#else
    asm("v_mfma_f32_16x16x16_bf16 %0, %1, %2, %0" : "+v"(c) : "v"(a), "v"(b));
    return c;
#endif
}

__device__ __forceinline__ u16 f2bf(float f) {
    union { float f; unsigned u; } v; v.f = f;
    unsigned u = v.u;
    u += 0x7FFFu + ((u >> 16) & 1u);   // RNE
    return (u16)(u >> 16);
}
__device__ __forceinline__ short tbf(float f) {   // truncating fp32->bf16
    union { float f; unsigned u; } v; v.f = f;
    return (short)(v.u >> 16);
}
// exp2 via compiler-known TRANS op (inline-asm v_exp_f32 lacks the TRANS->VALU
// hazard wait states -> corruption; learned round 3). -inf -> 0.
__device__ __forceinline__ float fexp2(float x) {
#if __has_builtin(__builtin_amdgcn_exp2f)
    return __builtin_amdgcn_exp2f(x);
#else
    return exp2f(x);
#endif
}

// async global->LDS, 16B per lane; LDS dest must be wave-uniform base (+lane*16 by HW)
__device__ __forceinline__ void gl_lds16(const void* g, void* s) {
    __builtin_amdgcn_global_load_lds(
        (__attribute__((address_space(1))) void*)g,
        (__attribute__((address_space(3))) void*)s,
        16, 0, 0);
}

// ---------------- stage 1a: x fp32 -> bf16 ----------------
__global__ void cvt_x(const float* __restrict__ x, u16* __restrict__ xb, int n4) {
    int i = blockIdx.x * blockDim.x + threadIdx.x;
    if (i < n4) {
        float4 v = ((const float4*)x)[i];
        ushort4 o;
        o.x = f2bf(v.x); o.y = f2bf(v.y); o.z = f2bf(v.z); o.w = f2bf(v.w);
        ((ushort4*)xb)[i] = o;
    }
}

// ---------------- stage 1b: Wq/Wk/Wv [H][C][HS] fp32 -> WT[z][h*64+d][c] bf16 ----------------
__global__ void transpose_w(const float* __restrict__ Wq, const float* __restrict__ Wk,
                            const float* __restrict__ Wv, u16* __restrict__ WT) {
    __shared__ float tile[64][65];
    const int tid = threadIdx.x;
    const int c0  = blockIdx.x * 64;   // C-tile
    const int h   = blockIdx.y;
    const int z   = blockIdx.z;
    const float* W = (z == 0 ? Wq : (z == 1 ? Wk : Wv)) + (size_t)h * 1024 * 64;
    u16* out = WT + (size_t)z * 1024 * 1024 + (size_t)h * 64 * 1024;
    #pragma unroll
    for (int i = 0; i < 16; ++i) {
        int idx = i * 256 + tid;
        int r = idx >> 6, d = idx & 63;          // read W[c0+r][d], coalesced in d
        tile[d][r] = W[(size_t)(c0 + r) * 64 + d];
    }
    __syncthreads();
    #pragma unroll
    for (int i = 0; i < 16; ++i) {
        int idx = i * 256 + tid;
        int d = idx >> 6, j = idx & 63;          // write out[d][c0+j], coalesced in j
        out[(size_t)d * 1024 + c0 + j] = f2bf(tile[d][j]);
    }
}

// ---------------- stage 1c: Wproj [C][C] fp32 -> WpT[n][c] bf16 ----------------
__global__ void transpose_p(const float* __restrict__ Wp, u16* __restrict__ WpT) {
    __shared__ float tile[64][65];
    const int tid = threadIdx.x;
    const int c0  = blockIdx.x * 64;
    const int n0  = blockIdx.y * 64;
    #pragma unroll
    for (int i = 0; i < 16; ++i) {
        int idx = i * 256 + tid;
        int r = idx >> 6, j = idx & 63;          // Wp[c0+r][n0+j]
        tile[j][r] = Wp[(size_t)(c0 + r) * 1024 + n0 + j];
    }
    __syncthreads();
    #pragma unroll
    for (int i = 0; i < 16; ++i) {
        int idx = i * 256 + tid;
        int r = idx >> 6, j = idx & 63;          // WpT[n0+r][c0+j]
        WpT[(size_t)(n0 + r) * 1024 + c0 + j] = f2bf(tile[r][j]);
    }
}

// ---------------- bf16 GEMM v3: BK=64 + 8-slot XOR swizzle ----------------
// C[m][n] = A[m][k] * Bt[n][k]^T. vs round-8 (BK=32, 6.5M bank conflicts, 30% Mfma):
//  - BK 32->64: halves barrier pairs + vmcnt drains (32->16 K-steps), 2x MFMA per
//    staged tile. LDS 32KB (As+Bs 16KB each).
//  - 8-slot XOR swizzle on both tiles: with BK=64 the row stride is 128B (every row
//    starts at bank 0 -> unswizzled would be 16-way conflict; BK=32 was 8-way =
//    the measured 6.5M). phys 16B-chunk p of row holds logical chunk p^(row&7);
//    inverse applied on the gl_lds GLOBAL SOURCE (proven involution pattern from
//    attn10/11's K tile); reads use chunk (kk*4+quad)^(l16&7) -> 2-way = free.
// Q scaled by C^-0.5*log2e for exp2-softmax; z==2 V^T epilogue bounces through LDS.
template <int MODE>
__global__ __launch_bounds__(256, 2)
void gemm_bt(const u16* __restrict__ A, const u16* __restrict__ Bt,
             u16* __restrict__ Oq, u16* __restrict__ Ok, u16* __restrict__ Ov,
             float* __restrict__ Op, const float* __restrict__ bias) {
    constexpr int K = 1024;
    __shared__ __align__(16) u16 SH[2][128 * 64];   // SH[0]=As, SH[1]=Bs; 32KB
    u16* As = SH[0];
    u16* Bs = SH[1];
    const int tid  = threadIdx.x;
    const int w    = tid >> 6;
    const int lane = tid & 63;
    const int quad = lane >> 4;
    const int l16  = lane & 15;
    const int m0   = blockIdx.x * 128;
    const int n0   = blockIdx.y * 128;
    const u16* Bp  = (MODE == 0) ? (Bt + (size_t)blockIdx.z * 1024 * 1024) : Bt;

    const f32x4 zero = {0.f, 0.f, 0.f, 0.f};
    f32x4 acc[4][4];
    #pragma unroll
    for (int i = 0; i < 4; ++i)
        #pragma unroll
        for (int j = 0; j < 4; ++j) acc[i][j] = zero;

    const int wr = (w >> 1) * 64;
    const int wc = (w & 1) * 64;
    const int rsw = l16 & 7;            // read-side row-XOR (rows of a frag share l16&7)

    // stage one 128x64 tile (16KB = 1024 x 16B chunks): 4 gl_lds per thread.
    // chunk j: row j>>3, in-row slot j&7; source col-chunk = (j&7) ^ (row&7).
    auto stage = [&](const u16* G, int gr0, int k0, u16* dst) {
        #pragma unroll
        for (int i = 0; i < 4; ++i) {
            int j = i * 256 + tid;
            int row = j >> 3;
            int sch = (j & 7) ^ (row & 7);
            gl_lds16(G + (size_t)(gr0 + row) * K + k0 + sch * 8,
                     dst + (size_t)(i * 256 + w * 64) * 8);
        }
    };

    for (int k0 = 0; k0 < K; k0 += 64) {
        __syncthreads();
        stage(A,  m0, k0, As);
        stage(Bp, n0, k0, Bs);
        __syncthreads();
        #pragma unroll
        for (int kk = 0; kk < 2; ++kk) {
            bf16x8 af[4], bfr[4];
            const int pch = ((kk * 4 + quad) ^ rsw) * 8;   // phys u16 offset in row
            #pragma unroll
            for (int i = 0; i < 4; ++i)
                af[i] = *(const bf16x8*)&As[(wr + i * 16 + l16) * 64 + pch];
            #pragma unroll
            for (int j = 0; j < 4; ++j)
                bfr[j] = *(const bf16x8*)&Bs[(wc + j * 16 + l16) * 64 + pch];
            #pragma unroll
            for (int i = 0; i < 4; ++i)
                #pragma unroll
                for (int j = 0; j < 4; ++j)
                    acc[i][j] = MFMA_BF16(af[i], bfr[j], acc[i][j]);
        }
    }

    // epilogue: C/D layout row=(quad*4+r), col=l16 within each 16x16 frag (m89/m91-verified)
    if (MODE == 0 && blockIdx.z == 2) {
        // V^T output: Ov[(bh*64+d)][t] -- bounce through LDS for coalesced stores.
        u32* buf = (u32*)SH;             // 16KB = 128*32 u32 fits in As region
        const int bh0 = (m0 >> 11) * 16;
        #pragma unroll
        for (int mh = 0; mh < 2; ++mh) {
            __syncthreads();           // K-loop reads / previous pass reads done
            if ((w >> 1) == mh) {
                #pragma unroll
                for (int i = 0; i < 4; ++i)
                    #pragma unroll
                    for (int j = 0; j < 4; ++j)
                        #pragma unroll
                        for (int rp = 0; rp < 2; ++rp) {
                            const int nl = wc + j * 16 + l16;       // 0..127
                            const int t2 = i * 8 + quad * 2 + rp;   // t-pair idx in pass
                            const u32 lo = f2bf(acc[i][j][2 * rp]);
                            const u32 hi = f2bf(acc[i][j][2 * rp + 1]);
                            buf[nl * 32 + (t2 ^ ((nl & 7) << 2))] = lo | (hi << 16);
                        }
            }
            __syncthreads();
            const int nl = tid >> 1, half = tid & 1;
            const int h = (n0 + nl) >> 6, d = (n0 + nl) & 63;
            u16* orow = Ov + ((size_t)(bh0 + h) * 64 + d) * 2048 + (m0 & 2047) + mh * 64;
            #pragma unroll
            for (int c = 0; c < 4; ++c) {
                const int d2b = half * 16 + c * 4;
                uint4 vv = *(const uint4*)&buf[nl * 32 + (d2b ^ ((nl & 7) << 2))];
                *(uint4*)(orow + d2b * 2) = vv;
            }
        }
    } else {
        #pragma unroll
        for (int i = 0; i < 4; ++i) {
            #pragma unroll
            for (int j = 0; j < 4; ++j) {
                #pragma unroll
                for (int r = 0; r < 4; ++r) {
                    const int m = m0 + wr + i * 16 + quad * 4 + r;
                    const int n = n0 + wc + j * 16 + l16;
                    const float v = acc[i][j][r];
                    if (MODE == 0) {
                        const int b = m >> 11, t = m & 2047;
                        const int h = n >> 6, d = n & 63;
                        const int bh = b * 16 + h;
                        if (blockIdx.z == 0)   // scale C^-0.5 * log2(e) for exp2-softmax
                            Oq[((size_t)bh * 2048 + t) * 64 + d] = f2bf(v * 0.0450842203f);
                        else
                            Ok[((size_t)bh * 2048 + t) * 64 + d] = f2bf(v);
                    } else {
                        Op[(size_t)m * 1024 + n] = v + bias[n];
                    }
                }
            }
        }
    }
}

// ---------------- flash attention v11: XCD-local K/V mapping (round-8 best) ----------
// grid dim3(64 bh, 8 xi): XCD = bh % 8 under round-robin; each XCD serves 8 bh
// (4MB K/V = one L2), all 8 blocks sharing a bh co-located. Balanced fwd/rev pairing.
// V staged via global_load_lds into linear [64][128] with row-XOR swizzle on the
// GLOBAL SOURCE; one barrier per K-iter; K tiles 4-slot XOR-swizzled.
// Q,K: [bh][T][64] bf16 (Q pre-scaled); Vt: [bh][64][T]; O -> Xo [b*T][1024] bf16.
__global__ __launch_bounds__(256, 2)
void attn11(const u16* __restrict__ Q, const u16* __restrict__ Kg,
            const u16* __restrict__ Vt, u16* __restrict__ O) {
    __shared__ __align__(16) u16 Ks[2][2 * 128 * 32];  // double-buffered K  32KB
    __shared__ __align__(16) u16 Vs[2][64 * 128];      // double-buffered V  32KB (+O-bounce)
    const int tid  = threadIdx.x;
    const int w    = tid >> 6;          // 0..3
    const int lane = tid & 63;
    const int quad = lane >> 4;
    const int l16  = lane & 15;
    const int bh   = blockIdx.x;        // XCD = bh % 8 under round-robin
    const int xi   = blockIdx.y;
    const u16* Qp = Q  + (size_t)bh * 2048 * 64;
    const u16* Kp = Kg + (size_t)bh * 2048 * 64;
    const u16* Vp = Vt + (size_t)bh * 64 * 2048;
    const int b = bh >> 4, h = bh & 15;
    const float NEG_INF = -__builtin_inff();
    const f32x4 zero = {0.f, 0.f, 0.f, 0.f};
    const short ONE = (short)0x3F80;    // bf16 1.0
    const bf16x4 vones = {ONE, ONE, ONE, ONE};
    const int ksw = ((l16 >> 1) & 3) << 3;   // read-side K swizzle (u16 units, 4-slot)

    // stage one 128x64 K tile (16KB): 16 wave-instrs; chunk-in-row XOR (row>>1)&3
    auto stageK = [&](int sb, u16* dst) {
        #pragma unroll
        for (int i = 0; i < 4; ++i) {
            int c = i * 256 + tid;
            int kk = c >> 9, row = (c >> 2) & 127;
            int q4s = (c & 3) ^ ((row >> 1) & 3);
            gl_lds16(Kp + (size_t)(sb + row) * 64 + kk * 32 + q4s * 8,
                     dst + (size_t)(i * 256 + w * 64) * 8);
        }
    };
    // stage one 64x128 V^T tile (16KB) into linear [64][128] with row-XOR swizzle:
    // phys 16B-chunk (d, ci) holds logical (d, ci ^ (d&7)); inverse applied on source.
    auto stageV = [&](int sb, u16* dst) {
        #pragma unroll
        for (int i = 0; i < 4; ++i) {
            int j = 4 * w + i;               // 16 instrs, 4 rows each
            int d = j * 4 + quad;
            int ci = l16 ^ (d & 7);
            gl_lds16(Vp + (size_t)d * 2048 + sb + ci * 8, dst + (size_t)j * 512);
        }
    };
    // PV A-frag read: V^T[d][s..s+3] from swizzled Vs (8B-aligned, 2-way banks = free)
    auto ldv = [&](const u16* Vc, int d, int s) -> bf16x4 {
        int off  = d * 128 + s;
        int phys = (off & 7) | (((off >> 3) ^ (d & 7)) << 3);
        return *(const bf16x4*)&Vc[phys];
    };

    #pragma unroll
    for (int ph = 0; ph < 2; ++ph) {
        const int tt = ph ? xi : 15 - xi;
        const int t0 = tt * 128;
        const int ns = tt + 1;

        // Q B-frags for this phase's 32 t-rows per wave
        bf16x8 bq[2][2];
        #pragma unroll
        for (int tf = 0; tf < 2; ++tf)
            #pragma unroll
            for (int kk = 0; kk < 2; ++kk)
                bq[tf][kk] = *(const bf16x8*)(Qp + (size_t)(t0 + w * 32 + tf * 16 + l16) * 64
                                              + kk * 32 + quad * 8);

        f32x4 oacc[4][2];
        f32x4 lacc[2] = {zero, zero};   // ones-MFMA softmax denominator, per tf
        #pragma unroll
        for (int df = 0; df < 4; ++df)
            #pragma unroll
            for (int tf = 0; tf < 2; ++tf) oacc[df][tf] = zero;

        __syncthreads();                 // prior phase's LDS reads (incl. O-bounce) done
        stageK(0, Ks[0]);
        stageV(0, Vs[0]);

        for (int it = 0; it < ns; ++it) {
            const int s0 = it * 128;
            __syncthreads();             // drains gl_lds(it) [vmcnt0 in syncthreads];
                                         // all waves past compute(it-1) -> restage safe
            if (it + 1 < ns) {
                stageK(s0 + 128, Ks[(it + 1) & 1]);
                stageV(s0 + 128, Vs[(it + 1) & 1]);
            }

            // ---- compute tile it ----
            const u16* Kc = Ks[it & 1];
            const u16* Vc = Vs[it & 1];
            const bool diag = (it == ns - 1);
            bf16x4 bp[8][2];
            #pragma unroll
            for (int st = 0; st < 8; ++st) {
                const int kbase = (st * 16 + l16) * 32 + quad * 8;
                bf16x8 ak0 = *(const bf16x8*)&Kc[kbase ^ ksw];
                bf16x8 ak1 = *(const bf16x8*)&Kc[(128 * 32) + (kbase ^ ksw)];
                #pragma unroll
                for (int tf = 0; tf < 2; ++tf) {
                    f32x4 s = MFMA_BF16(ak0, bq[tf][0], zero);
                    s = MFMA_BF16(ak1, bq[tf][1], s);
                    if (diag) {
                        #pragma unroll
                        for (int r = 0; r < 4; ++r) {
                            int ss = s0 + st * 16 + quad * 4 + r;
                            int t  = t0 + w * 32 + tf * 16 + l16;
                            if (ss > t) s[r] = NEG_INF;
                        }
                    }
                    float p0 = fexp2(s[0]), p1 = fexp2(s[1]);
                    float p2 = fexp2(s[2]), p3 = fexp2(s[3]);
                    bf16x4 bb; bb[0] = tbf(p0); bb[1] = tbf(p1);
                    bb[2] = tbf(p2); bb[3] = tbf(p3);
                    bp[st][tf] = bb;
                }
            }
            // denominator: lacc[tf][*] += ones . P
            #pragma unroll
            for (int st = 0; st < 8; ++st)
                #pragma unroll
                for (int tf = 0; tf < 2; ++tf)
                    lacc[tf] = mfma16(vones, bp[st][tf], lacc[tf]);
            // O^T += V^T P^T : A-frags from swizzled Vs, B = bp (regs)
            #pragma unroll
            for (int kcp = 0; kcp < 4; ++kcp)
                #pragma unroll
                for (int df = 0; df < 4; ++df) {
                    const int d = df * 16 + l16;
                    bf16x4 alo = ldv(Vc, d, kcp * 32 + quad * 4);
                    bf16x4 ahi = ldv(Vc, d, kcp * 32 + 16 + quad * 4);
                    #pragma unroll
                    for (int tf = 0; tf < 2; ++tf) {
                        oacc[df][tf] = mfma16(alo, bp[2 * kcp][tf], oacc[df][tf]);
                        oacc[df][tf] = mfma16(ahi, bp[2 * kcp + 1][tf], oacc[df][tf]);
                    }
                }
        }

        // epilogue: bounce O-tile [t 128][d 64] through Vs, store coalesced dwordx4.
        __syncthreads();                 // all waves done reading Ks/Vs this phase
        {
            u32* ob = (u32*)Vs;
            const float inv[2] = {1.0f / lacc[0][0], 1.0f / lacc[1][0]};
            #pragma unroll
            for (int df = 0; df < 4; ++df)
                #pragma unroll
                for (int tf = 0; tf < 2; ++tf) {
                    const int tl = w * 32 + tf * 16 + l16;
                    #pragma unroll
                    for (int rp = 0; rp < 2; ++rp) {
                        const u32 lo = f2bf(oacc[df][tf][2 * rp]     * inv[tf]);
                        const u32 hi = f2bf(oacc[df][tf][2 * rp + 1] * inv[tf]);
                        const int d2 = df * 8 + quad * 2 + rp;
                        ob[tl * 32 + (d2 ^ ((tl & 7) << 2))] = lo | (hi << 16);
                    }
                }
            __syncthreads();
            const int tl = tid >> 1, half = tid & 1;
            u16* orow = O + ((size_t)(b * 2048 + t0 + tl)) * 1024 + h * 64;
            #pragma unroll
            for (int c = 0; c < 4; ++c) {
                const int d2b = half * 16 + c * 4;
                uint4 vv = *(const uint4*)&ob[tl * 32 + (d2b ^ ((tl & 7) << 2))];
                *(uint4*)(orow + d2b * 2) = vv;
            }
        }
    }
}

extern "C" void kernel_launch(void* const* d_in, const int* in_sizes, int n_in,
                              void* d_out, int out_size, void* d_ws, size_t ws_size,
                              hipStream_t stream) {
    const float* x  = (const float*)d_in[0];
    const float* Wq = (const float*)d_in[1];
    const float* Wk = (const float*)d_in[2];
    const float* Wv = (const float*)d_in[3];
    const float* Wp = (const float*)d_in[4];
    const float* bp = (const float*)d_in[5];
    float* out = (float*)d_out;

    char* ws = (char*)d_ws;
    // layout (bytes): Xb/Xo share region 0 (Xb dead before attn writes Xo)
    u16* Xb  = (u16*)(ws);                          // [8192][1024] bf16 (16 MB)
    u16* Xo  = (u16*)(ws);                          // attn output, same region
    u16* WT  = (u16*)(ws + (16ull << 20));          // 3 x [1024][1024] (6 MB)
    u16* WpT = (u16*)(ws + (22ull << 20));          // [1024][1024] (2 MB)
    u16* Qw  = (u16*)(ws + (24ull << 20));          // [64][2048][64] (16 MB)
    u16* Kw  = (u16*)(ws + (40ull << 20));          // [64][2048][64] (16 MB)
    u16* Vw  = (u16*)(ws + (56ull << 20));          // [64][64][2048] (16 MB)
    // total 72 MB

    cvt_x<<<8192, 256, 0, stream>>>(x, Xb, 8192 * 1024 / 4);
    transpose_w<<<dim3(16, 16, 3), 256, 0, stream>>>(Wq, Wk, Wv, WT);
    transpose_p<<<dim3(16, 16), 256, 0, stream>>>(Wp, WpT);
    gemm_bt<0><<<dim3(64, 8, 3), 256, 0, stream>>>(Xb, WT, Qw, Kw, Vw, nullptr, nullptr);
    attn11<<<dim3(64, 8), 256, 0, stream>>>(Qw, Kw, Vw, Xo);
    gemm_bt<1><<<dim3(64, 8, 1), 256, 0, stream>>>(Xo, WpT, nullptr, nullptr, nullptr, out, bp);
}